// Round 1
// baseline (251.750 us; speedup 1.0000x reference)
//
#include <hip/hip_runtime.h>
#include <hip/hip_bf16.h>
#include <math.h>

// Problem constants (B, C, LQ, LK) from the reference.
constexpr int NB  = 8;
constexpr int NC  = 128;
constexpr int NLQ = 2048;
constexpr int NLK = 2048;
constexpr int QT  = 32;          // q-rows per block
constexpr int SPAD = 2056;       // strip row stride in halves (+8 pad: breaks pow2 bank stride)
#define SCALE 0.08838834764831845f   // 1/sqrt(128)

typedef _Float16 h8  __attribute__((ext_vector_type(8)));
typedef _Float16 h4v __attribute__((ext_vector_type(4)));
typedef float    f4  __attribute__((ext_vector_type(4)));

// Fragment conventions for v_mfma_f32_16x16x32_f16 (wave64):
//   A[m][kc]: m = lane&15, kc = (lane>>4)*8 + j   (j = 0..7)
//   B[kc][n]: n = lane&15, kc = (lane>>4)*8 + j
//   D reg r : row m = (lane>>4)*4 + r, col n = lane&15   [HW-verified, learn_hip m89]
// A/B use the same (lane,j)->kc map, so any contraction-permutation cancels.

__global__ __launch_bounds__(512, 2)
void attn_fused(const float* __restrict__ Qp, const float* __restrict__ Kp,
                const float* __restrict__ Vp, const int* __restrict__ Mp,
                float* __restrict__ outP, float* __restrict__ attnP)
{
    __shared__ _Float16 Sh[QT][SPAD];     // e' strip, later attention (fp16)
    __shared__ float mred[4][QT];         // per-k-quarter row maxima
    __shared__ float sred[4][QT];         // per-k-quarter row exp-sums

    const int tid  = threadIdx.x;
    const int w    = tid >> 6;            // wave id 0..7
    const int lane = tid & 63;
    const int lo   = lane & 15;
    const int g    = lane >> 4;           // 16-lane group 0..3
    const int qg   = w & 1;               // q half-tile (16 rows)
    const int nh   = w >> 1;              // k quarter (512 cols) / c quarter in PV
    const int b    = blockIdx.y;
    const int q0   = blockIdx.x * QT;

    // ---- Preload Q A-fragments (4 c-chunks of 32), kept in registers ----
    h8 aQ[4];
    {
        const int q = q0 + qg * 16 + lo;
        #pragma unroll
        for (int cc = 0; cc < 4; ++cc) {
            const float* qp = &Qp[((size_t)(b * NC + cc * 32 + g * 8)) * NLQ + q];
            #pragma unroll
            for (int j = 0; j < 8; ++j) aQ[cc][j] = (_Float16)qp[(size_t)j * NLQ];
        }
    }

    // ---- QK^T, scale, mask->-inf, running row max; store e' (fp16) to strip ----
    float mx[4] = {-INFINITY, -INFINITY, -INFINITY, -INFINITY};
    for (int t = 0; t < 32; ++t) {
        const int n0 = nh * 512 + t * 16;
        f4 d = {0.f, 0.f, 0.f, 0.f};
        #pragma unroll
        for (int cc = 0; cc < 4; ++cc) {
            const float* kp = &Kp[((size_t)(b * NC + cc * 32 + g * 8)) * NLK + n0 + lo];
            h8 bk;
            #pragma unroll
            for (int j = 0; j < 8; ++j) bk[j] = (_Float16)kp[(size_t)j * NLK];
            d = __builtin_amdgcn_mfma_f32_16x16x32_f16(aQ[cc], bk, d, 0, 0, 0);
        }
        const int* mp = &Mp[((size_t)(b * NLQ + q0 + qg * 16 + g * 4)) * NLK + n0 + lo];
        #pragma unroll
        for (int r = 0; r < 4; ++r) {
            float e = d[r] * SCALE;
            const int mv = mp[(size_t)r * NLK];
            e = mv ? e : -INFINITY;       // masked: exact 0 after exp; ~1e-9 rel denom effect
            const _Float16 eh = (_Float16)e;
            mx[r] = fmaxf(mx[r], (float)eh);   // max over the *rounded* values
            Sh[qg * 16 + g * 4 + r][n0 + lo] = eh;
        }
    }
    #pragma unroll
    for (int off = 1; off < 16; off <<= 1) {
        #pragma unroll
        for (int r = 0; r < 4; ++r) mx[r] = fmaxf(mx[r], __shfl_xor(mx[r], off));
    }
    if (lo == 0) {
        #pragma unroll
        for (int r = 0; r < 4; ++r) mred[nh][qg * 16 + g * 4 + r] = mx[r];
    }
    __syncthreads();

    // ---- denominator sweep (each wave: its 16 rows x its 512-col quarter) ----
    for (int rr = 0; rr < 16; ++rr) {
        const int row = qg * 16 + rr;
        float m = fmaxf(fmaxf(mred[0][row], mred[1][row]), fmaxf(mred[2][row], mred[3][row]));
        if (m < -1e30f) m = 0.f;          // all-masked row guard
        float s = 0.f;
        #pragma unroll
        for (int it = 0; it < 2; ++it) {
            const int kb = nh * 512 + it * 256 + lane * 4;
            h4v v = *(const h4v*)&Sh[row][kb];
            s += __expf((float)v[0] - m) + __expf((float)v[1] - m)
               + __expf((float)v[2] - m) + __expf((float)v[3] - m);
        }
        #pragma unroll
        for (int off = 1; off < 64; off <<= 1) s += __shfl_xor(s, off);
        if (lane == 0) sred[nh][row] = s;
    }
    __syncthreads();

    // ---- attention sweep: f32 to global, fp16 back into strip for PV ----
    for (int rr = 0; rr < 16; ++rr) {
        const int row = qg * 16 + rr;
        float m = fmaxf(fmaxf(mred[0][row], mred[1][row]), fmaxf(mred[2][row], mred[3][row]));
        if (m < -1e30f) m = 0.f;
        const float s = sred[0][row] + sred[1][row] + sred[2][row] + sred[3][row];
        const float inv = s > 0.f ? 1.0f / s : 0.f;
        #pragma unroll
        for (int it = 0; it < 2; ++it) {
            const int kb = nh * 512 + it * 256 + lane * 4;
            h4v v = *(const h4v*)&Sh[row][kb];
            f4 a;
            #pragma unroll
            for (int i = 0; i < 4; ++i) a[i] = __expf((float)v[i] - m) * inv;
            *(f4*)&attnP[((size_t)(b * NLQ + q0 + row)) * NLK + kb] = a;
            h4v hv;
            #pragma unroll
            for (int i = 0; i < 4; ++i) hv[i] = (_Float16)a[i];
            *(h4v*)&Sh[row][kb] = hv;
        }
    }
    __syncthreads();

    // ---- PV: out[q][c] = sum_k attn[q][k] * V[c][k], wave: (qg, c-quarter nh) ----
    f4 acc[2] = {{0.f,0.f,0.f,0.f},{0.f,0.f,0.f,0.f}};
    for (int kt = 0; kt < 64; ++kt) {
        const int k0 = kt * 32;
        const h8 a = *(const h8*)&Sh[qg * 16 + lo][k0 + g * 8];
        #pragma unroll
        for (int ct = 0; ct < 2; ++ct) {
            const int c = nh * 32 + ct * 16 + lo;
            const float* vp = &Vp[((size_t)(b * NC + c)) * NLK + k0 + g * 8];
            const f4 v0 = *(const f4*)vp;
            const f4 v1 = *(const f4*)(vp + 4);
            h8 bv;
            #pragma unroll
            for (int j = 0; j < 4; ++j) { bv[j] = (_Float16)v0[j]; bv[4 + j] = (_Float16)v1[j]; }
            acc[ct] = __builtin_amdgcn_mfma_f32_16x16x32_f16(a, bv, acc[ct], 0, 0, 0);
        }
    }
    #pragma unroll
    for (int ct = 0; ct < 2; ++ct) {
        const int c = nh * 32 + ct * 16 + lo;
        const int q = q0 + qg * 16 + g * 4;
        *(f4*)&outP[((size_t)(b * NC + c)) * NLQ + q] = acc[ct];
    }
}

extern "C" void kernel_launch(void* const* d_in, const int* in_sizes, int n_in,
                              void* d_out, int out_size, void* d_ws, size_t ws_size,
                              hipStream_t stream) {
    const float* Qp = (const float*)d_in[0];
    const float* Kp = (const float*)d_in[1];
    const float* Vp = (const float*)d_in[2];
    const int*   Mp = (const int*)d_in[3];
    float* outP  = (float*)d_out;
    float* attnP = outP + (size_t)NB * NC * NLQ;   // outputs concatenated: out, attention

    dim3 grid(NLQ / QT, NB);   // 64 x 8 = 512 blocks
    attn_fused<<<grid, dim3(512), 0, stream>>>(Qp, Kp, Vp, Mp, outP, attnP);
}

// Round 2
// 172.450 us; speedup vs baseline: 1.4598x; 1.4598x over previous
//
#include <hip/hip_runtime.h>
#include <hip/hip_bf16.h>
#include <math.h>

// B=8, C=128, LQ=LK=2048. Outputs: out (B,C,LQ) then attention (B,LQ,LK), f32.
constexpr int NB  = 8;
constexpr int NC  = 128;
constexpr int NLQ = 2048;
constexpr int NLK = 2048;
#define SCALE 0.08838834764831845f   // 1/sqrt(128)

typedef _Float16 h8  __attribute__((ext_vector_type(8)));
typedef _Float16 h4v __attribute__((ext_vector_type(4)));
typedef float    f4  __attribute__((ext_vector_type(4)));

// ---------------- pre-pass: f32 [b][C][L] -> fp16 [b][L][C] (transpose) ----------------
__global__ __launch_bounds__(256)
void trans_f32_h16(const float* __restrict__ in, _Float16* __restrict__ out)
{
    __shared__ float tile[32][33];
    const int b  = blockIdx.z;
    const int l0 = blockIdx.x * 32;
    const int c0 = blockIdx.y * 32;
    const int tx = threadIdx.x, ty = threadIdx.y;      // 32 x 8
    const float* ip = in + ((size_t)(b * NC + c0 + ty)) * NLK + l0 + tx;
    #pragma unroll
    for (int j = 0; j < 4; ++j)
        tile[ty + j * 8][tx] = ip[(size_t)j * 8 * NLK];
    __syncthreads();
    _Float16* op = out + ((size_t)(b * NLK + l0 + ty)) * NC + c0 + tx;
    #pragma unroll
    for (int j = 0; j < 4; ++j)
        op[(size_t)j * 8 * NC] = (_Float16)tile[tx][ty + j * 8];
}

// ---------------- pre-pass: f32 -> fp16 elementwise (V keeps [b][C][L]) ----------------
__global__ __launch_bounds__(256)
void cvt_f32_h16(const float* __restrict__ in, _Float16* __restrict__ out, int n4)
{
    const int i = blockIdx.x * blockDim.x + threadIdx.x;
    if (i < n4) {
        const f4 v = *(const f4*)&in[(size_t)i * 4];
        h4v h;
        #pragma unroll
        for (int j = 0; j < 4; ++j) h[j] = (_Float16)v[j];
        *(h4v*)&out[(size_t)i * 4] = h;
    }
}

// ---------------- main fused kernel: 16 q-rows per block, 8 waves own k-octants ----------------
// MFMA f32_16x16x32_f16 conventions (contraction map identical for A and B, so it cancels):
//   A[m][kc]: m=lane&15, kc=(lane>>4)*8+j ;  B[kc][n]: n=lane&15, kc=(lane>>4)*8+j
//   D reg r: row=(lane>>4)*4+r, col=lane&15   [HW-verified]
constexpr int SP = 2072;   // strip stride in halves: 4144 B = 16B-aligned, bank-uniform

__global__ __launch_bounds__(512, 4)
void attn_main(const _Float16* __restrict__ Qt, const _Float16* __restrict__ Kt,
               const _Float16* __restrict__ Vh, const int* __restrict__ Mp,
               float* __restrict__ outP, float* __restrict__ attnP)
{
    __shared__ _Float16 Sh[16][SP];
    __shared__ float mred[8][16];
    __shared__ float sred[8][16];

    const int tid  = threadIdx.x;
    const int w    = tid >> 6;          // wave 0..7: k-octant (QK/softmax), c-tile (PV)
    const int lane = tid & 63;
    const int lo   = lane & 15;
    const int g    = lane >> 4;

    // XCD-bijective swizzle: 1024 blocks, XCD x owns batch x (Kt/Vh ~1MB -> L2-resident)
    const int bid = blockIdx.x;
    const int b   = bid & 7;
    const int q0  = (bid >> 3) * 16;

    // ---- Q A-fragments: 4 chunks of 32 channels, one h8 load each ----
    h8 aQ[4];
    {
        const _Float16* qr = &Qt[((size_t)(b * NLQ + q0 + lo)) * NC];
        #pragma unroll
        for (int cc = 0; cc < 4; ++cc) aQ[cc] = *(const h8*)&qr[cc * 32 + g * 8];
    }

    // ---- QK^T + scale + mask -> e' strip (fp16), partial row max ----
    float mx[4] = {-INFINITY, -INFINITY, -INFINITY, -INFINITY};
    for (int t = 0; t < 16; ++t) {
        const int n0 = w * 256 + t * 16;
        f4 d = {0.f, 0.f, 0.f, 0.f};
        const _Float16* kr = &Kt[((size_t)(b * NLK + n0 + lo)) * NC + g * 8];
        #pragma unroll
        for (int cc = 0; cc < 4; ++cc)
            d = __builtin_amdgcn_mfma_f32_16x16x32_f16(aQ[cc], *(const h8*)&kr[cc * 32], d, 0, 0, 0);
        const int* mp = &Mp[((size_t)(b * NLQ + q0 + g * 4)) * NLK + n0 + lo];
        #pragma unroll
        for (int r = 0; r < 4; ++r) {
            float e = d[r] * SCALE;
            const int mv = mp[(size_t)r * NLK];
            e = mv ? e : -INFINITY;               // exact 0 after exp; matches ref to ~1e-9
            const _Float16 eh = (_Float16)e;
            mx[r] = fmaxf(mx[r], (float)eh);
            Sh[g * 4 + r][n0 + lo] = eh;
        }
    }
    #pragma unroll
    for (int off = 1; off < 16; off <<= 1) {
        #pragma unroll
        for (int r = 0; r < 4; ++r) mx[r] = fmaxf(mx[r], __shfl_xor(mx[r], off));
    }
    if (lo == 0) {
        #pragma unroll
        for (int r = 0; r < 4; ++r) mred[w][g * 4 + r] = mx[r];
    }
    __syncthreads();

    // ---- single-exp pass: p = exp(e'-m) stored back fp16; per-octant row sums ----
    for (int rr = 0; rr < 16; ++rr) {
        float m = -INFINITY;
        #pragma unroll
        for (int i = 0; i < 8; ++i) m = fmaxf(m, mred[i][rr]);
        if (m < -1e30f) m = 0.f;                  // all-masked row guard
        const int col = w * 256 + lane * 4;
        const h4v v = *(const h4v*)&Sh[rr][col];
        h4v ph;
        float s = 0.f;
        #pragma unroll
        for (int i = 0; i < 4; ++i) {
            const _Float16 p = (_Float16)__expf((float)v[i] - m);
            ph[i] = p;
            s += (float)p;
        }
        *(h4v*)&Sh[rr][col] = ph;
        #pragma unroll
        for (int off = 1; off < 64; off <<= 1) s += __shfl_xor(s, off);
        if (lane == 0) sred[w][rr] = s;
    }
    __syncthreads();

    // ---- scale pass: attention f32 to global, scaled fp16 back to strip for PV ----
    for (int rr = 0; rr < 16; ++rr) {
        float S = 0.f;
        #pragma unroll
        for (int i = 0; i < 8; ++i) S += sred[i][rr];
        const float inv = S > 0.f ? 1.0f / S : 0.f;
        const int col = w * 256 + lane * 4;
        const h4v v = *(const h4v*)&Sh[rr][col];
        f4 a;
        h4v hv;
        #pragma unroll
        for (int i = 0; i < 4; ++i) {
            a[i] = (float)v[i] * inv;
            hv[i] = (_Float16)a[i];
        }
        *(f4*)&attnP[((size_t)(b * NLQ + q0 + rr)) * NLK + col] = a;
        *(h4v*)&Sh[rr][col] = hv;
    }
    __syncthreads();

    // ---- PV: out[q][c] = sum_k P[q][k] V[c][k]; wave w owns c-tile w*16..w*16+15 ----
    f4 acc = {0.f, 0.f, 0.f, 0.f};
    const _Float16* vr = &Vh[((size_t)(b * NC + w * 16 + lo)) * NLK];
    for (int kt = 0; kt < 64; ++kt) {
        const int k0 = kt * 32;
        const h8 a  = *(const h8*)&Sh[lo][k0 + g * 8];
        const h8 bv = *(const h8*)&vr[k0 + g * 8];
        acc = __builtin_amdgcn_mfma_f32_16x16x32_f16(a, bv, acc, 0, 0, 0);
    }
    *(f4*)&outP[((size_t)(b * NC + w * 16 + lo)) * NLQ + q0 + g * 4] = acc;
}

// ---------------- fallback (round-1 kernel, used only if ws_size is too small) ----------------
constexpr int QT_F = 32;
constexpr int SPAD_F = 2056;

__global__ __launch_bounds__(512, 2)
void attn_fallback(const float* __restrict__ Qp, const float* __restrict__ Kp,
                   const float* __restrict__ Vp, const int* __restrict__ Mp,
                   float* __restrict__ outP, float* __restrict__ attnP)
{
    __shared__ _Float16 Sh[QT_F][SPAD_F];
    __shared__ float mred[4][QT_F];
    __shared__ float sred[4][QT_F];

    const int tid  = threadIdx.x;
    const int w    = tid >> 6;
    const int lane = tid & 63;
    const int lo   = lane & 15;
    const int g    = lane >> 4;
    const int qg   = w & 1;
    const int nh   = w >> 1;
    const int b    = blockIdx.y;
    const int q0   = blockIdx.x * QT_F;

    h8 aQ[4];
    {
        const int q = q0 + qg * 16 + lo;
        #pragma unroll
        for (int cc = 0; cc < 4; ++cc) {
            const float* qp = &Qp[((size_t)(b * NC + cc * 32 + g * 8)) * NLQ + q];
            #pragma unroll
            for (int j = 0; j < 8; ++j) aQ[cc][j] = (_Float16)qp[(size_t)j * NLQ];
        }
    }
    float mx[4] = {-INFINITY, -INFINITY, -INFINITY, -INFINITY};
    for (int t = 0; t < 32; ++t) {
        const int n0 = nh * 512 + t * 16;
        f4 d = {0.f, 0.f, 0.f, 0.f};
        #pragma unroll
        for (int cc = 0; cc < 4; ++cc) {
            const float* kp = &Kp[((size_t)(b * NC + cc * 32 + g * 8)) * NLK + n0 + lo];
            h8 bk;
            #pragma unroll
            for (int j = 0; j < 8; ++j) bk[j] = (_Float16)kp[(size_t)j * NLK];
            d = __builtin_amdgcn_mfma_f32_16x16x32_f16(aQ[cc], bk, d, 0, 0, 0);
        }
        const int* mp = &Mp[((size_t)(b * NLQ + q0 + qg * 16 + g * 4)) * NLK + n0 + lo];
        #pragma unroll
        for (int r = 0; r < 4; ++r) {
            float e = d[r] * SCALE;
            const int mv = mp[(size_t)r * NLK];
            e = mv ? e : -INFINITY;
            const _Float16 eh = (_Float16)e;
            mx[r] = fmaxf(mx[r], (float)eh);
            Sh[qg * 16 + g * 4 + r][n0 + lo] = eh;
        }
    }
    #pragma unroll
    for (int off = 1; off < 16; off <<= 1) {
        #pragma unroll
        for (int r = 0; r < 4; ++r) mx[r] = fmaxf(mx[r], __shfl_xor(mx[r], off));
    }
    if (lo == 0) {
        #pragma unroll
        for (int r = 0; r < 4; ++r) mred[nh][qg * 16 + g * 4 + r] = mx[r];
    }
    __syncthreads();
    for (int rr = 0; rr < 16; ++rr) {
        const int row = qg * 16 + rr;
        float m = fmaxf(fmaxf(mred[0][row], mred[1][row]), fmaxf(mred[2][row], mred[3][row]));
        if (m < -1e30f) m = 0.f;
        float s = 0.f;
        #pragma unroll
        for (int it = 0; it < 2; ++it) {
            const int kb = nh * 512 + it * 256 + lane * 4;
            h4v v = *(const h4v*)&Sh[row][kb];
            s += __expf((float)v[0] - m) + __expf((float)v[1] - m)
               + __expf((float)v[2] - m) + __expf((float)v[3] - m);
        }
        #pragma unroll
        for (int off = 1; off < 64; off <<= 1) s += __shfl_xor(s, off);
        if (lane == 0) sred[nh][row] = s;
    }
    __syncthreads();
    for (int rr = 0; rr < 16; ++rr) {
        const int row = qg * 16 + rr;
        float m = fmaxf(fmaxf(mred[0][row], mred[1][row]), fmaxf(mred[2][row], mred[3][row]));
        if (m < -1e30f) m = 0.f;
        const float s = sred[0][row] + sred[1][row] + sred[2][row] + sred[3][row];
        const float inv = s > 0.f ? 1.0f / s : 0.f;
        #pragma unroll
        for (int it = 0; it < 2; ++it) {
            const int kb = nh * 512 + it * 256 + lane * 4;
            h4v v = *(const h4v*)&Sh[row][kb];
            f4 a;
            #pragma unroll
            for (int i = 0; i < 4; ++i) a[i] = __expf((float)v[i] - m) * inv;
            *(f4*)&attnP[((size_t)(b * NLQ + q0 + row)) * NLK + kb] = a;
            h4v hv;
            #pragma unroll
            for (int i = 0; i < 4; ++i) hv[i] = (_Float16)a[i];
            *(h4v*)&Sh[row][kb] = hv;
        }
    }
    __syncthreads();
    f4 acc[2] = {{0.f,0.f,0.f,0.f},{0.f,0.f,0.f,0.f}};
    for (int kt = 0; kt < 64; ++kt) {
        const int k0 = kt * 32;
        const h8 a = *(const h8*)&Sh[qg * 16 + lo][k0 + g * 8];
        #pragma unroll
        for (int ct = 0; ct < 2; ++ct) {
            const int c = nh * 32 + ct * 16 + lo;
            const float* vp = &Vp[((size_t)(b * NC + c)) * NLK + k0 + g * 8];
            const f4 v0 = *(const f4*)vp;
            const f4 v1 = *(const f4*)(vp + 4);
            h8 bv;
            #pragma unroll
            for (int j = 0; j < 4; ++j) { bv[j] = (_Float16)v0[j]; bv[4 + j] = (_Float16)v1[j]; }
            acc[ct] = __builtin_amdgcn_mfma_f32_16x16x32_f16(a, bv, acc[ct], 0, 0, 0);
        }
    }
    #pragma unroll
    for (int ct = 0; ct < 2; ++ct) {
        const int c = nh * 32 + ct * 16 + lo;
        const int q = q0 + qg * 16 + g * 4;
        *(f4*)&outP[((size_t)(b * NC + c)) * NLQ + q] = acc[ct];
    }
}

extern "C" void kernel_launch(void* const* d_in, const int* in_sizes, int n_in,
                              void* d_out, int out_size, void* d_ws, size_t ws_size,
                              hipStream_t stream) {
    const float* Qp = (const float*)d_in[0];
    const float* Kp = (const float*)d_in[1];
    const float* Vp = (const float*)d_in[2];
    const int*   Mp = (const int*)d_in[3];
    float* outP  = (float*)d_out;
    float* attnP = outP + (size_t)NB * NC * NLQ;

    const size_t telem = (size_t)NB * NC * NLK;        // 2,097,152 per tensor
    const size_t need  = 3 * telem * sizeof(_Float16); // 12,582,912 B

    if (ws_size >= need) {
        _Float16* Qt = (_Float16*)d_ws;
        _Float16* Kt = Qt + telem;
        _Float16* Vh = Kt + telem;
        dim3 tb(32, 8);
        trans_f32_h16<<<dim3(NLQ / 32, NC / 32, NB), tb, 0, stream>>>(Qp, Qt);
        trans_f32_h16<<<dim3(NLK / 32, NC / 32, NB), tb, 0, stream>>>(Kp, Kt);
        cvt_f32_h16<<<(int)(telem / 4 + 255) / 256, 256, 0, stream>>>(Vp, Vh, (int)(telem / 4));
        attn_main<<<dim3(NB * (NLQ / 16)), dim3(512), 0, stream>>>(Qt, Kt, Vh, Mp, outP, attnP);
    } else {
        dim3 grid(NLQ / QT_F, NB);
        attn_fallback<<<grid, dim3(512), 0, stream>>>(Qp, Kp, Vp, Mp, outP, attnP);
    }
}